// Round 8
// baseline (2685.527 us; speedup 1.0000x reference)
//
#include <hip/hip_runtime.h>
#include <stdint.h>

// HeadwiseLowRankModule: out = blockdiag-GEMM(GEMM(hidden, VT^T), U^T), f32 I/O.
// GEMM1: 256x256-tile 8-phase pipeline. THIS ROUND: accumulators FORCED into
// AGPRs via "+a" no-op asm (r4-r7 evidence: 128-arch-VGPR hard cap + acc in
// arch regs -> every A/B fragment spills each phase ~= the constant 3.1-3.4GB
// scratch traffic). waves_per_eu(2,2). Schedule unchanged (refcheck'd 4x).
// GEMM2: proven m97 128x128 kernel.

typedef short  bf16x8  __attribute__((ext_vector_type(8)));
typedef float  f32x4   __attribute__((ext_vector_type(4)));
typedef ushort ushort8 __attribute__((ext_vector_type(8)));
typedef float  flt4    __attribute__((ext_vector_type(4)));

__device__ __forceinline__ void gload_lds16(const ushort* g, ushort* l) {
    __builtin_amdgcn_global_load_lds(
        (const __attribute__((address_space(1))) uint32_t*)g,
        (__attribute__((address_space(3))) uint32_t*)l, 16, 0, 0);
}

__device__ __forceinline__ ushort f2bf(float f) {
    union { float f; uint32_t u; } c; c.f = f;
    uint32_t u = c.u;
    uint32_t r = (u + 0x7FFFu + ((u >> 16) & 1u)) >> 16;  // RNE
    return (ushort)r;
}

__device__ __forceinline__ void cfence() { asm volatile("" ::: "memory"); }

template<int N> __device__ __forceinline__ void vwait() {
    if constexpr (N == 8)      asm volatile("s_waitcnt vmcnt(8)" ::: "memory");
    else if constexpr (N == 4) asm volatile("s_waitcnt vmcnt(4)" ::: "memory");
    else if constexpr (N == 2) asm volatile("s_waitcnt vmcnt(2)" ::: "memory");
    else if constexpr (N == 0) asm volatile("s_waitcnt vmcnt(0)" ::: "memory");
    // N < 0: no wait
}

// ---- f32 -> bf16 conversion ----
__global__ __launch_bounds__(256) void f32_to_bf16_kernel(
    const float* __restrict__ in, ushort* __restrict__ out, long n8)
{
    const long stride = (long)gridDim.x * blockDim.x;
    for (long i = (long)blockIdx.x * blockDim.x + threadIdx.x; i < n8; i += stride) {
        flt4 a = ((const flt4*)in)[2 * i];
        flt4 b = ((const flt4*)in)[2 * i + 1];
        ushort8 o;
        o[0] = f2bf(a[0]); o[1] = f2bf(a[1]); o[2] = f2bf(a[2]); o[3] = f2bf(a[3]);
        o[4] = f2bf(b[0]); o[5] = f2bf(b[1]); o[6] = f2bf(b[2]); o[7] = f2bf(b[3]);
        ((ushort8*)out)[i] = o;
    }
}

// =====================================================================
// GEMM1: 256x256 tile, BK=64, 8 waves (2Mx4N), 8-phase pipeline.
// Named regs: a0..a7, b0..b3 (bf16x8), c0..c31 (f32x4, PINNED TO AGPR).
// Swizzle byteOff ^= (row&7)<<4. Stage schedule identical to r4-r7
// (uniform vmcnt(8), tail 4->2->0).
// =====================================================================

#define ARD(BUF, MG, MF, KK) \
    (*(const bf16x8*)&(BUF)[(((MG)*128 + wr*64 + (MF)*16 + l15) * 64) + \
                            (((((KK)<<2) | lq) ^ l7) << 3)])
#define BRD(BUF, NG, NF, KK) \
    (*(const bf16x8*)&(BUF)[(((NG)*128 + wc*32 + (NF)*16 + l15) * 64) + \
                            (((((KK)<<2) | lq) ^ l7) << 3)])

#define RD_A(BUF, MG) \
    a0 = ARD(BUF,MG,0,0); a1 = ARD(BUF,MG,0,1); \
    a2 = ARD(BUF,MG,1,0); a3 = ARD(BUF,MG,1,1); \
    a4 = ARD(BUF,MG,2,0); a5 = ARD(BUF,MG,2,1); \
    a6 = ARD(BUF,MG,3,0); a7 = ARD(BUF,MG,3,1);
#define RD_B(BUF, NG) \
    b0 = BRD(BUF,NG,0,0); b1 = BRD(BUF,NG,0,1); \
    b2 = BRD(BUF,NG,1,0); b3 = BRD(BUF,NG,1,1);

#define STAGE_A(H, KT, ABUF) do { \
    const ushort* _g = aSt + (H)*128*LDA + (KT)*64; \
    gload_lds16(_g,            (ABUF) + (H)*8192 + ldsoff0); \
    gload_lds16(_g + 64*LDA,   (ABUF) + (H)*8192 + ldsoff1); \
} while (0)
#define STAGE_B(H, KT, BBUF) do { \
    const ushort* _g = bSt + (H)*128*LDB + (KT)*64; \
    gload_lds16(_g,            (BBUF) + (H)*8192 + ldsoff0); \
    gload_lds16(_g + 64*LDB,   (BBUF) + (H)*8192 + ldsoff1); \
} while (0)

#define MFMA2(CI, AA0, AA1, BB0, BB1) \
    CI = __builtin_amdgcn_mfma_f32_16x16x32_bf16(AA0, BB0, CI, 0, 0, 0); \
    CI = __builtin_amdgcn_mfma_f32_16x16x32_bf16(AA1, BB1, CI, 0, 0, 0);

// quadrant (MG,NG): c{MG*16 + mf*4 + NG*2 + nf}, a{mf*2+kk}, b{nf*2+kk}
#define MFMA_Q00 \
    MFMA2(c0,a0,a1,b0,b1)  MFMA2(c1,a0,a1,b2,b3)  MFMA2(c4,a2,a3,b0,b1)  MFMA2(c5,a2,a3,b2,b3) \
    MFMA2(c8,a4,a5,b0,b1)  MFMA2(c9,a4,a5,b2,b3)  MFMA2(c12,a6,a7,b0,b1) MFMA2(c13,a6,a7,b2,b3)
#define MFMA_Q01 \
    MFMA2(c2,a0,a1,b0,b1)  MFMA2(c3,a0,a1,b2,b3)  MFMA2(c6,a2,a3,b0,b1)  MFMA2(c7,a2,a3,b2,b3) \
    MFMA2(c10,a4,a5,b0,b1) MFMA2(c11,a4,a5,b2,b3) MFMA2(c14,a6,a7,b0,b1) MFMA2(c15,a6,a7,b2,b3)
#define MFMA_Q10 \
    MFMA2(c16,a0,a1,b0,b1) MFMA2(c17,a0,a1,b2,b3) MFMA2(c20,a2,a3,b0,b1) MFMA2(c21,a2,a3,b2,b3) \
    MFMA2(c24,a4,a5,b0,b1) MFMA2(c25,a4,a5,b2,b3) MFMA2(c28,a6,a7,b0,b1) MFMA2(c29,a6,a7,b2,b3)
#define MFMA_Q11 \
    MFMA2(c18,a0,a1,b0,b1) MFMA2(c19,a0,a1,b2,b3) MFMA2(c22,a2,a3,b0,b1) MFMA2(c23,a2,a3,b2,b3) \
    MFMA2(c26,a4,a5,b0,b1) MFMA2(c27,a4,a5,b2,b3) MFMA2(c30,a6,a7,b0,b1) MFMA2(c31,a6,a7,b2,b3)

// Pin all 32 accumulators to AGPRs ("a" = accumulator register class).
// Two asms of 16 operands each (stay under inline-asm operand limits).
#define PIN_ACC \
    asm volatile("" : "+a"(c0),"+a"(c1),"+a"(c2),"+a"(c3),"+a"(c4),"+a"(c5), \
                      "+a"(c6),"+a"(c7),"+a"(c8),"+a"(c9),"+a"(c10),"+a"(c11), \
                      "+a"(c12),"+a"(c13),"+a"(c14),"+a"(c15)); \
    asm volatile("" : "+a"(c16),"+a"(c17),"+a"(c18),"+a"(c19),"+a"(c20),"+a"(c21), \
                      "+a"(c22),"+a"(c23),"+a"(c24),"+a"(c25),"+a"(c26),"+a"(c27), \
                      "+a"(c28),"+a"(c29),"+a"(c30),"+a"(c31));

#define PH_TAIL(QM, W) \
    __builtin_amdgcn_s_barrier(); \
    __builtin_amdgcn_s_setprio(1); \
    QM \
    __builtin_amdgcn_s_setprio(0); \
    vwait<W>(); \
    __builtin_amdgcn_s_barrier(); \
    cfence();

#define TILE_BODY(CA, CB, OA, OB, KT1, KT2, S0, S1, S2, S3, W0, W1, W2, W3) do { \
    /* p0: read A mg0 + B ng0; stage R4(KT1)->other B */ \
    RD_A(CA, 0) RD_B(CB, 0) \
    if (S0) { STAGE_B(1, KT1, OB); } \
    PH_TAIL(MFMA_Q00, W0) \
    /* p1: read B ng1; stage R3(KT1)->other A */ \
    RD_B(CB, 1) \
    if (S1) { STAGE_A(1, KT1, OA); } \
    PH_TAIL(MFMA_Q01, W1) \
    /* p2: read A mg1 + B ng0 (re-read); stage R1(KT2)->cur A (free after p0) */ \
    RD_A(CA, 1) RD_B(CB, 0) \
    if (S2) { STAGE_A(0, KT2, CA); } \
    PH_TAIL(MFMA_Q10, W2) \
    /* p3: read B ng1 (re-read); stage R2(KT2)->cur B (free after p0) */ \
    RD_B(CB, 1) \
    if (S3) { STAGE_B(0, KT2, CB); } \
    PH_TAIL(MFMA_Q11, W3) \
    PIN_ACC \
} while (0)

// epilogue store: C/D layout col = lane&15, row = (lane>>4)*4 + reg
#define EPI(CI, MG, MF, NG, NF) { \
    const int rowb_ = row0 + (MG)*128 + wr*64 + (MF)*16 + lq*4; \
    const int colb_ = col0 + (NG)*128 + wc*32 + (NF)*16 + l15; \
    C[(size_t)(rowb_ + 0) * LDC + colb_] = f2bf(CI[0]); \
    C[(size_t)(rowb_ + 1) * LDC + colb_] = f2bf(CI[1]); \
    C[(size_t)(rowb_ + 2) * LDC + colb_] = f2bf(CI[2]); \
    C[(size_t)(rowb_ + 3) * LDC + colb_] = f2bf(CI[3]); }

template<int LDA, int LDB, int LDC, int KDIM>
__global__ __launch_bounds__(512)
__attribute__((amdgpu_waves_per_eu(2, 2)))
void gemm256_bf16(
    const ushort* __restrict__ A, const ushort* __restrict__ B,
    ushort* __restrict__ C)
{
    __shared__ ushort lds[65536];  // 128 KiB static: 1 wg/CU (2 waves/SIMD)
    ushort* A0 = lds;              // buf0 A: 256x64 elems (32 KiB)
    ushort* B0 = lds + 16384;
    ushort* A1 = lds + 32768;
    ushort* B1 = lds + 49152;

    const int tid  = threadIdx.x;
    const int lane = tid & 63;
    const int wave = tid >> 6;       // 0..7
    const int wr = wave >> 2;        // 0..1
    const int wc = wave & 3;         // 0..3

    // XCD-locality mapping: x (N-tile) fastest -> each XCD keeps one VT panel
    const int bx = blockIdx.x & 7;
    const int by = blockIdx.x >> 3;
    const int row0 = by * 256;
    const int col0 = bx * 256;

    const int l15 = lane & 15;
    const int lq  = lane >> 4;       // 0..3
    const int l7  = lane & 7;

    // staging constants: linear idx = j*512 + tid; row = idx>>3; chunk swizzle
    const int srow = tid >> 3;                              // j=0 row (j=1: +64)
    const int scsw = (((tid & 7) ^ (srow & 7)) << 3);       // swizzled col (elems)
    const int ldsoff0 = (wave * 64) * 8;                    // wave-uniform dests
    const int ldsoff1 = (512 + wave * 64) * 8;

    // hoisted per-thread global staging bases
    const ushort* aSt = A + (size_t)(row0 + srow) * LDA + scsw;
    const ushort* bSt = B + (size_t)(col0 + srow) * LDB + scsw;

    // named registers; accumulators pinned to AGPRs via PIN_ACC
    f32x4 c0={},c1={},c2={},c3={},c4={},c5={},c6={},c7={},
          c8={},c9={},c10={},c11={},c12={},c13={},c14={},c15={},
          c16={},c17={},c18={},c19={},c20={},c21={},c22={},c23={},
          c24={},c25={},c26={},c27={},c28={},c29={},c30={},c31={};
    bf16x8 a0,a1,a2,a3,a4,a5,a6,a7;
    bf16x8 b0,b1,b2,b3;

    constexpr int nkt = KDIM >> 6;

    // Prologue: stage R1(0),R2(0),R4(0),R3(0),R1(1),R2(1)
    STAGE_A(0, 0, A0);
    STAGE_B(0, 0, B0);
    STAGE_B(1, 0, B0);
    STAGE_A(1, 0, A0);
    STAGE_A(0, 1, A1);
    STAGE_B(0, 1, B1);
    PIN_ACC
    vwait<8>();                       // R1(0),R2(0) complete
    __builtin_amdgcn_s_barrier();
    cfence();

    for (int t = 0; t < nkt - 2; ++t) {
        if ((t & 1) == 0) TILE_BODY(A0, B0, A1, B1, t+1, t+2, 1,1,1,1, 8,8,8,8);
        else              TILE_BODY(A1, B1, A0, B0, t+1, t+2, 1,1,1,1, 8,8,8,8);
    }
    {   // tail tile nkt-2: stage only R4/R3(nkt-1); drain to 4
        const int t = nkt - 2;
        if ((t & 1) == 0) TILE_BODY(A0, B0, A1, B1, t+1, 0, 1,1,0,0, 8,8,8,4);
        else              TILE_BODY(A1, B1, A0, B0, t+1, 0, 1,1,0,0, 8,8,8,4);
    }
    {   // tail tile nkt-1: no staging; drain 2 -> 0
        const int t = nkt - 1;
        if ((t & 1) == 0) TILE_BODY(A0, B0, A1, B1, 0, 0, 0,0,0,0, 2,0,-1,-1);
        else              TILE_BODY(A1, B1, A0, B0, 0, 0, 0,0,0,0, 2,0,-1,-1);
    }

    // Epilogue: c{mg*16+mf*4+ng*2+nf}
    EPI(c0,0,0,0,0)   EPI(c1,0,0,0,1)   EPI(c2,0,0,1,0)   EPI(c3,0,0,1,1)
    EPI(c4,0,1,0,0)   EPI(c5,0,1,0,1)   EPI(c6,0,1,1,0)   EPI(c7,0,1,1,1)
    EPI(c8,0,2,0,0)   EPI(c9,0,2,0,1)   EPI(c10,0,2,1,0)  EPI(c11,0,2,1,1)
    EPI(c12,0,3,0,0)  EPI(c13,0,3,0,1)  EPI(c14,0,3,1,0)  EPI(c15,0,3,1,1)
    EPI(c16,1,0,0,0)  EPI(c17,1,0,0,1)  EPI(c18,1,0,1,0)  EPI(c19,1,0,1,1)
    EPI(c20,1,1,0,0)  EPI(c21,1,1,0,1)  EPI(c22,1,1,1,0)  EPI(c23,1,1,1,1)
    EPI(c24,1,2,0,0)  EPI(c25,1,2,0,1)  EPI(c26,1,2,1,0)  EPI(c27,1,2,1,1)
    EPI(c28,1,3,0,0)  EPI(c29,1,3,0,1)  EPI(c30,1,3,1,0)  EPI(c31,1,3,1,1)
}

// ---- store helpers ----
__device__ __forceinline__ void store_out(ushort* p, float v) { *p = f2bf(v); }
__device__ __forceinline__ void store_out(float*  p, float v) { *p = v; }

// GEMM2: proven m97-style 128x128 kernel (block-diagonal via blockIdx.z)
template <typename TOUT>
__global__ __launch_bounds__(256) void gemm_bt_kernel(
    const ushort* __restrict__ A,
    const ushort* __restrict__ B,
    TOUT* __restrict__ C,
    int lda, int ldb, int ldc, int K,
    long aOffZ, long bOffZ, long cOffZ)
{
    A += (size_t)blockIdx.z * aOffZ;
    B += (size_t)blockIdx.z * bOffZ;
    C += (size_t)blockIdx.z * cOffZ;

    __shared__ ushort As[128 * 64];
    __shared__ ushort Bs[128 * 64];

    const int tid  = threadIdx.x;
    const int lane = tid & 63;
    const int wave = tid >> 6;

    const int row0 = blockIdx.y * 128;
    const int col0 = blockIdx.x * 128;

    const int wr = wave >> 1;
    const int wc = wave & 1;

    const int l15    = lane & 15;
    const int lq     = lane >> 4;
    const int lrow   = lane >> 3;
    const int lchunk = lane & 7;

    f32x4 acc[4][4] = {};

    const ushort* aPtr = A + (size_t)(row0 + wave * 32 + lrow) * lda + lchunk * 8;
    const ushort* bPtr = B + (size_t)(col0 + wave * 32 + lrow) * ldb + lchunk * 8;

    const int nkt = K / 64;
    for (int kt = 0; kt < nkt; ++kt) {
        const int kOff = kt * 64;
        __syncthreads();
        #pragma unroll
        for (int i = 0; i < 4; ++i) {
            gload_lds16(aPtr + (size_t)i * 8 * lda + kOff, As + (wave * 4 + i) * 512);
            gload_lds16(bPtr + (size_t)i * 8 * ldb + kOff, Bs + (wave * 4 + i) * 512);
        }
        __syncthreads();

        #pragma unroll
        for (int kk = 0; kk < 2; ++kk) {
            bf16x8 af[4], bfr[4];
            #pragma unroll
            for (int m = 0; m < 4; ++m)
                af[m] = *(const bf16x8*)&As[(wr * 64 + m * 16 + l15) * 64 + kk * 32 + lq * 8];
            #pragma unroll
            for (int n = 0; n < 4; ++n)
                bfr[n] = *(const bf16x8*)&Bs[(wc * 64 + n * 16 + l15) * 64 + kk * 32 + lq * 8];
            #pragma unroll
            for (int m = 0; m < 4; ++m)
                #pragma unroll
                for (int n = 0; n < 4; ++n)
                    acc[m][n] = __builtin_amdgcn_mfma_f32_16x16x32_bf16(
                        af[m], bfr[n], acc[m][n], 0, 0, 0);
        }
    }

    #pragma unroll
    for (int m = 0; m < 4; ++m) {
        #pragma unroll
        for (int r = 0; r < 4; ++r) {
            const size_t row = (size_t)(row0 + wr * 64 + m * 16 + lq * 4 + r);
            TOUT* cRow = C + row * ldc + col0 + wc * 64 + l15;
            #pragma unroll
            for (int n = 0; n < 4; ++n)
                store_out(cRow + n * 16, acc[m][n][r]);
        }
    }
}

extern "C" void kernel_launch(void* const* d_in, const int* in_sizes, int n_in,
                              void* d_out, int out_size, void* d_ws, size_t ws_size,
                              hipStream_t stream) {
    const float* hidden_f = (const float*)d_in[0];  // 16384 x 4096 f32
    const float* VT_f     = (const float*)d_in[1];  // 2048 x 4096 f32 (N,K)
    const float* U_f      = (const float*)d_in[2];  // 8 x 512 x 256 f32
    float* out = (float*)d_out;                     // 16384 x 4096 f32

    const long nHid = 16384L * 4096L;
    const long nVT  = 2048L * 4096L;
    const long nU   = 8L * 512L * 256L;
    const long nLat = 16384L * 2048L;

    ushort *hid_b, *vt_b, *u_b, *lat_b;
    const size_t needA = (size_t)(nHid + nVT + nU + nLat) * 2;
    if (ws_size >= needA) {
        ushort* w = (ushort*)d_ws;
        hid_b = w;  vt_b = hid_b + nHid;  u_b = vt_b + nVT;  lat_b = u_b + nU;
    } else {
        ushort* w = (ushort*)d_ws;
        lat_b = w;  u_b = lat_b + nLat;
        ushort* o = (ushort*)d_out;       // staged in d_out; fully overwritten by GEMM2
        hid_b = o;  vt_b = hid_b + nHid;
    }

    dim3 cblk(256, 1, 1);
    f32_to_bf16_kernel<<<dim3(2048), cblk, 0, stream>>>(hidden_f, hid_b, nHid / 8);
    f32_to_bf16_kernel<<<dim3(1024), cblk, 0, stream>>>(VT_f, vt_b, nVT / 8);
    f32_to_bf16_kernel<<<dim3(256),  cblk, 0, stream>>>(U_f,  u_b,  nU / 8);

    // GEMM1: latent[16384 x 2048] = hid * VT^T  (256^2 8-phase, static LDS)
    gemm256_bf16<4096, 4096, 2048, 4096><<<dim3(512), dim3(512), 0, stream>>>(
        hid_b, vt_b, lat_b);

    // GEMM2 (block-diag): out[:, g*512:+512] = latent[:, g*256:+256] * U[g]^T
    dim3 g2(512 / 128, 16384 / 128, 8);
    gemm_bt_kernel<float><<<g2, dim3(256), 0, stream>>>(lat_b, u_b, out,
                                                        2048, 256, 4096, 256,
                                                        256L, 512L * 256L, 512L);
}

// Round 9
// 545.266 us; speedup vs baseline: 4.9252x; 4.9252x over previous
//
#include <hip/hip_runtime.h>
#include <stdint.h>

// HeadwiseLowRankModule: out = blockdiag-GEMM(GEMM(hidden, VT^T), U^T), f32 I/O.
// ROUND 9: full revert to the round-2 PROVEN configuration (549us):
//   GEMM1 = m97-style 128x128 tile, BK=64, global_load_lds(16B), 4 waves.
//   GEMM2 = same kernel, block-diagonal via blockIdx.z, f32 out.
// The 256^2 8-phase experiment (r3-r8) is abandoned: a hard 128-VGPR
// allocator cap caused GB-scale scratch spills under 5 different fixes.
// Only change vs r2: the three f32->bf16 convert launches merged into one.

typedef short  bf16x8  __attribute__((ext_vector_type(8)));
typedef float  f32x4   __attribute__((ext_vector_type(4)));
typedef ushort ushort8 __attribute__((ext_vector_type(8)));
typedef float  flt4    __attribute__((ext_vector_type(4)));

__device__ __forceinline__ void gload_lds16(const ushort* g, ushort* l) {
    __builtin_amdgcn_global_load_lds(
        (const __attribute__((address_space(1))) uint32_t*)g,
        (__attribute__((address_space(3))) uint32_t*)l, 16, 0, 0);
}

__device__ __forceinline__ ushort f2bf(float f) {
    union { float f; uint32_t u; } c; c.f = f;
    uint32_t u = c.u;
    uint32_t r = (u + 0x7FFFu + ((u >> 16) & 1u)) >> 16;  // RNE
    return (ushort)r;
}

// ---- fused f32 -> bf16 conversion for all three inputs (one launch) ----
// Block ranges: [0,1792) hidden, [1792,2016) VT, [2016,2048) U.
__device__ __forceinline__ void conv_seg(const float* __restrict__ in,
                                         ushort* __restrict__ out,
                                         long n8, int bid, int nblk) {
    const long stride = (long)nblk * 256;
    for (long i = (long)bid * 256 + threadIdx.x; i < n8; i += stride) {
        flt4 a = ((const flt4*)in)[2 * i];
        flt4 b = ((const flt4*)in)[2 * i + 1];
        ushort8 o;
        o[0] = f2bf(a[0]); o[1] = f2bf(a[1]); o[2] = f2bf(a[2]); o[3] = f2bf(a[3]);
        o[4] = f2bf(b[0]); o[5] = f2bf(b[1]); o[6] = f2bf(b[2]); o[7] = f2bf(b[3]);
        ((ushort8*)out)[i] = o;
    }
}

__global__ __launch_bounds__(256) void convert_all_kernel(
    const float* __restrict__ hid_f, ushort* __restrict__ hid_b, long nHid8,
    const float* __restrict__ vt_f,  ushort* __restrict__ vt_b,  long nVT8,
    const float* __restrict__ u_f,   ushort* __restrict__ u_b,   long nU8)
{
    const int b = blockIdx.x;
    if (b < 1792)      conv_seg(hid_f, hid_b, nHid8, b,        1792);
    else if (b < 2016) conv_seg(vt_f,  vt_b,  nVT8,  b - 1792, 224);
    else               conv_seg(u_f,   u_b,   nU8,   b - 2016, 32);
}

// ---- store helpers (bf16 or f32 output) ----
__device__ __forceinline__ void store_out(ushort* p, float v) { *p = f2bf(v); }
__device__ __forceinline__ void store_out(float*  p, float v) { *p = v; }

// C[M x ldc] = A[. x lda] * B[. x ldb]^T  (A,B bf16 row-major, K contiguous)
// blockIdx.z applies flat element offsets (block-diagonal GEMM2).
// PROVEN r2 kernel: 128x128 tile, BK=64, 4 waves (2x2 of 64x64 sub-tiles).
template <typename TOUT>
__global__ __launch_bounds__(256) void gemm_bt_kernel(
    const ushort* __restrict__ A,
    const ushort* __restrict__ B,
    TOUT* __restrict__ C,
    int lda, int ldb, int ldc, int K,
    long aOffZ, long bOffZ, long cOffZ)
{
    A += (size_t)blockIdx.z * aOffZ;
    B += (size_t)blockIdx.z * bOffZ;
    C += (size_t)blockIdx.z * cOffZ;

    __shared__ ushort As[128 * 64];   // 16 KiB, linear (global_load_lds dest)
    __shared__ ushort Bs[128 * 64];   // 16 KiB

    const int tid  = threadIdx.x;
    const int lane = tid & 63;
    const int wave = tid >> 6;

    const int row0 = blockIdx.y * 128;
    const int col0 = blockIdx.x * 128;

    const int wr = wave >> 1;
    const int wc = wave & 1;

    const int l15    = lane & 15;
    const int lq     = lane >> 4;    // 0..3
    const int lrow   = lane >> 3;    // 0..7 (staging row in 8-row segment)
    const int lchunk = lane & 7;     // 0..7 (16B chunk within row)

    f32x4 acc[4][4] = {};

    const ushort* aPtr = A + (size_t)(row0 + wave * 32 + lrow) * lda + lchunk * 8;
    const ushort* bPtr = B + (size_t)(col0 + wave * 32 + lrow) * ldb + lchunk * 8;

    const int nkt = K / 64;
    for (int kt = 0; kt < nkt; ++kt) {
        const int kOff = kt * 64;
        __syncthreads();
        #pragma unroll
        for (int i = 0; i < 4; ++i) {
            gload_lds16(aPtr + (size_t)i * 8 * lda + kOff, As + (wave * 4 + i) * 512);
            gload_lds16(bPtr + (size_t)i * 8 * ldb + kOff, Bs + (wave * 4 + i) * 512);
        }
        __syncthreads();

        #pragma unroll
        for (int kk = 0; kk < 2; ++kk) {
            bf16x8 af[4], bfr[4];
            #pragma unroll
            for (int m = 0; m < 4; ++m)
                af[m] = *(const bf16x8*)&As[(wr * 64 + m * 16 + l15) * 64 + kk * 32 + lq * 8];
            #pragma unroll
            for (int n = 0; n < 4; ++n)
                bfr[n] = *(const bf16x8*)&Bs[(wc * 64 + n * 16 + l15) * 64 + kk * 32 + lq * 8];
            #pragma unroll
            for (int m = 0; m < 4; ++m)
                #pragma unroll
                for (int n = 0; n < 4; ++n)
                    acc[m][n] = __builtin_amdgcn_mfma_f32_16x16x32_bf16(
                        af[m], bfr[n], acc[m][n], 0, 0, 0);
        }
    }

    // C/D layout: col = lane&15, row = (lane>>4)*4 + reg  [m89/m91 verified]
    #pragma unroll
    for (int m = 0; m < 4; ++m) {
        #pragma unroll
        for (int r = 0; r < 4; ++r) {
            const size_t row = (size_t)(row0 + wr * 64 + m * 16 + lq * 4 + r);
            TOUT* cRow = C + row * ldc + col0 + wc * 64 + l15;
            #pragma unroll
            for (int n = 0; n < 4; ++n)
                store_out(cRow + n * 16, acc[m][n][r]);
        }
    }
}

extern "C" void kernel_launch(void* const* d_in, const int* in_sizes, int n_in,
                              void* d_out, int out_size, void* d_ws, size_t ws_size,
                              hipStream_t stream) {
    const float* hidden_f = (const float*)d_in[0];  // 16384 x 4096 f32
    const float* VT_f     = (const float*)d_in[1];  // 2048 x 4096 f32 (N,K)
    const float* U_f      = (const float*)d_in[2];  // 8 x 512 x 256 f32
    float* out = (float*)d_out;                     // 16384 x 4096 f32

    const long nHid = 16384L * 4096L;
    const long nVT  = 2048L * 4096L;
    const long nU   = 8L * 512L * 256L;
    const long nLat = 16384L * 2048L;

    ushort *hid_b, *vt_b, *u_b, *lat_b;
    const size_t needA = (size_t)(nHid + nVT + nU + nLat) * 2;
    if (ws_size >= needA) {
        ushort* w = (ushort*)d_ws;
        hid_b = w;  vt_b = hid_b + nHid;  u_b = vt_b + nVT;  lat_b = u_b + nU;
    } else {
        ushort* w = (ushort*)d_ws;
        lat_b = w;  u_b = lat_b + nLat;
        ushort* o = (ushort*)d_out;       // staged in d_out; fully overwritten by GEMM2
        hid_b = o;  vt_b = hid_b + nHid;
    }

    // fused input conversion (one launch)
    convert_all_kernel<<<dim3(2048), dim3(256), 0, stream>>>(
        hidden_f, hid_b, nHid / 8,
        VT_f,     vt_b,  nVT / 8,
        U_f,      u_b,   nU / 8);

    // GEMM1: latent[16384 x 2048] = hid[16384 x 4096] * VT[2048 x 4096]^T
    dim3 g1(2048 / 128, 16384 / 128, 1);
    gemm_bt_kernel<ushort><<<g1, dim3(256), 0, stream>>>(hid_b, vt_b, lat_b,
                                                         4096, 4096, 2048, 4096,
                                                         0L, 0L, 0L);

    // GEMM2 (block-diag): out[:, g*512:+512] = latent[:, g*256:+256] * U[g]^T
    dim3 g2(512 / 128, 16384 / 128, 8);
    gemm_bt_kernel<float><<<g2, dim3(256), 0, stream>>>(lat_b, u_b, out,
                                                        2048, 256, 4096, 256,
                                                        256L, 512L * 256L, 512L);
}